// Round 1
// baseline (782.829 us; speedup 1.0000x reference)
//
#include <hip/hip_runtime.h>

#define BSZ 64
#define QN  1024
#define TN  128
#define NCL 20
#define INFV 1e30f

// Kernel 1: softmax over classes, stored transposed probT[b][c][q] for
// coalesced per-class row reads in the LSA kernel.
__global__ void softmax_probT_kernel(const float* __restrict__ logits,
                                     float* __restrict__ probT) {
    int idx = blockIdx.x * blockDim.x + threadIdx.x; // b*QN + q
    if (idx >= BSZ * QN) return;
    int b = idx >> 10;
    int q = idx & (QN - 1);
    const float* row = logits + (size_t)idx * NCL;

    float x[NCL];
    float mx = -INFV;
#pragma unroll
    for (int c = 0; c < NCL; ++c) { x[c] = row[c]; mx = fmaxf(mx, x[c]); }
    float e[NCL];
    float s = 0.f;
#pragma unroll
    for (int c = 0; c < NCL; ++c) { e[c] = expf(x[c] - mx); s += e[c]; }
#pragma unroll
    for (int c = 0; c < NCL; ++c) {
        probT[((size_t)b * NCL + c) * QN + q] = e[c] / s;
    }
}

// Kernel 2: Jonker-Volgenant rectangular LSA, one wave (64 lanes) per batch.
// Rows = targets (n=128), cols = queries (m=1024). Each lane owns 16 columns
// c = slot*64 + lane. Replicates the reference's float op order exactly.
__global__ __launch_bounds__(64) void lsa_kernel(
    const float* __restrict__ pred_coords, // (B,Q,2)
    const int*   __restrict__ tgt_labels,  // (B,T)
    const float* __restrict__ tgt_joints,  // (B,T,2)
    const float* __restrict__ probT,       // (B,NC,Q)
    int*         __restrict__ out)         // pred_idx (B,T) ++ tgt_idx (B,T)
{
    const int b = blockIdx.x;
    const int lane = threadIdx.x;

    __shared__ float v_s[QN];
    __shared__ float spc_s[QN];
    __shared__ int   path_s[QN];
    __shared__ int   row4col_s[QN];
    __shared__ int   sc_s[QN];
    __shared__ float u_s[TN];
    __shared__ int   col4row_s[TN];

    // init block state
#pragma unroll
    for (int s = 0; s < 16; ++s) {
        int c = s * 64 + lane;
        v_s[c] = 0.f;
        row4col_s[c] = -1;
    }
    u_s[lane] = 0.f;       u_s[lane + 64] = 0.f;
    col4row_s[lane] = -1;  col4row_s[lane + 64] = -1;
    __syncthreads();

    const float2* pc   = (const float2*)pred_coords + (size_t)b * QN;
    const float*  pT   = probT + (size_t)b * NCL * QN;
    const int*    labs = tgt_labels + (size_t)b * TN;
    const float2* tj   = (const float2*)tgt_joints + (size_t)b * TN;

    for (int cur = 0; cur < TN; ++cur) {
        // per-row init (owner lanes only — no sync needed)
#pragma unroll
        for (int s = 0; s < 16; ++s) {
            int c = s * 64 + lane;
            spc_s[c] = INFV;
            path_s[c] = 0;
            sc_s[c] = 0;
        }

        float minVal = 0.f;
        int i = cur;
        int sink = -1;

        // shortest augmenting path (Dijkstra). Uniform loop; no barriers:
        // all LDS state touched here is lane-owned; j/minVal via shuffles.
        for (int guard = 0; sink < 0 && guard <= QN + 2; ++guard) {
            float u_i = u_s[i];          // uniform broadcast
            int   lab = labs[i];
            float2 t  = tj[i];
            const float* prow = pT + (size_t)lab * QN;

#pragma unroll
            for (int s = 0; s < 16; ++s) {
                int c = s * 64 + lane;
                if (!sc_s[c]) {
                    float2 p = pc[c];
                    float cb = fabsf(p.x - t.x) + fabsf(p.y - t.y);
                    float cost = cb + (-prow[c]);           // bbox + (-prob)
                    float r = ((minVal + cost) - u_i) - v_s[c];
                    if (r < spc_s[c]) { spc_s[c] = r; path_s[c] = i; }
                }
            }

            // masked argmin with first-index tie-break (matches jnp.argmin)
            float bv = INFV;
            int   bi = 0x7fffffff;
#pragma unroll
            for (int s = 0; s < 16; ++s) {
                int c = s * 64 + lane;
                float val = sc_s[c] ? INFV : spc_s[c];
                if (val < bv) { bv = val; bi = c; }  // slots ascending -> first idx kept
            }
            for (int off = 32; off > 0; off >>= 1) {
                float ov = __shfl_xor(bv, off);
                int   oi = __shfl_xor(bi, off);
                if (ov < bv || (ov == bv && oi < bi)) { bv = ov; bi = oi; }
            }
            minVal = bv;
            int j = bi;

            if (lane == (j & 63)) sc_s[j] = 1;   // owner lane writes own column
            int rj = row4col_s[j];               // only changes at augmentation
            sink = (rj < 0) ? j : -1;
            i = rj;
        }

        __syncthreads();   // publish spc/sc/path before cross-lane dual update

        // dual updates (exactly as reference)
        if (lane == 0) u_s[cur] += minVal;
        for (int rr = lane; rr < TN; rr += 64) {
            int c4 = col4row_s[rr];
            if (rr != cur && c4 >= 0 && sc_s[c4]) {
                u_s[rr] += (minVal - spc_s[c4]);
            }
        }
#pragma unroll
        for (int s = 0; s < 16; ++s) {
            int c = s * 64 + lane;
            if (sc_s[c]) v_s[c] -= (minVal - spc_s[c]);
        }

        __syncthreads();   // publish u/v before augmentation reads path/col4row

        // augment along alternating path (serial, lane 0)
        if (lane == 0) {
            int j = sink;
            for (int it = 0; it <= TN; ++it) {
                int ii = path_s[j];
                row4col_s[j] = ii;
                int nj = col4row_s[ii];
                col4row_s[ii] = j;
                j = nj;
                if (ii == cur) break;
            }
        }
        __syncthreads();
    }

    // outputs: order = argsort(col4row) (distinct values -> rank = #smaller)
    for (int t = lane; t < TN; t += 64) {
        int q = col4row_s[t];
        int rank = 0;
        for (int s = 0; s < TN; ++s) rank += (col4row_s[s] < q) ? 1 : 0;
        out[(size_t)b * TN + rank] = q;                    // pred_idx
        out[(size_t)(BSZ + b) * TN + rank] = t;            // tgt_idx
    }
}

extern "C" void kernel_launch(void* const* d_in, const int* in_sizes, int n_in,
                              void* d_out, int out_size, void* d_ws, size_t ws_size,
                              hipStream_t stream) {
    const float* pred_logits = (const float*)d_in[0]; // (B,Q,NC)
    const float* pred_coords = (const float*)d_in[1]; // (B,Q,2)
    const int*   tgt_labels  = (const int*)d_in[2];   // (B,T)
    const float* tgt_joints  = (const float*)d_in[3]; // (B,T,2)

    float* probT = (float*)d_ws;                      // (B,NC,Q) = 5.24 MB
    int*   out   = (int*)d_out;

    softmax_probT_kernel<<<(BSZ * QN + 255) / 256, 256, 0, stream>>>(pred_logits, probT);
    lsa_kernel<<<BSZ, 64, 0, stream>>>(pred_coords, tgt_labels, tgt_joints, probT, out);
}

// Round 2
// 351.646 us; speedup vs baseline: 2.2262x; 2.2262x over previous
//
#include <hip/hip_runtime.h>

#define BSZ 64
#define QN  1024
#define TN  128
#define NCL 20
#define INFV 1e30f

// One wave (64 lanes) per batch. Rows = targets (128), cols = queries (1024).
// Lane owns 16 columns c = s*64 + lane; spc/path/v/sc for those columns live
// in REGISTERS during the Dijkstra loop (dumped to LDS once per row-scan for
// the cross-lane dual update / augmentation). Softmax probs staged in LDS.
__global__ __launch_bounds__(64) void lsa_fused_kernel(
    const float* __restrict__ pred_logits, // (B,Q,NC)
    const float* __restrict__ pred_coords, // (B,Q,2)
    const int*   __restrict__ tgt_labels,  // (B,T)
    const float* __restrict__ tgt_joints,  // (B,T,2)
    int*         __restrict__ out)         // pred_idx (B,T) ++ tgt_idx (B,T)
{
    const int b = blockIdx.x;
    const int lane = threadIdx.x;

    __shared__ float prob_lds[NCL][QN];   // 80 KB
    __shared__ int   path_s[QN];          // 4 KB
    __shared__ int   row4col_s[QN];       // 4 KB
    __shared__ float spc_d[QN];           // 4 KB
    __shared__ int   sc_d[QN];            // 4 KB
    __shared__ int   col4row_s[TN];       // 512 B

    // ---- stage softmax(logits) into LDS, same op order as reference ----
    {
        const float* lg = pred_logits + (size_t)b * QN * NCL;
#pragma unroll
        for (int k = 0; k < 16; ++k) {
            int q = k * 64 + lane;
            const float4* rp = (const float4*)(lg + (size_t)q * NCL); // 80B rows, 16B aligned
            float x[NCL];
            *(float4*)&x[0]  = rp[0];
            *(float4*)&x[4]  = rp[1];
            *(float4*)&x[8]  = rp[2];
            *(float4*)&x[12] = rp[3];
            *(float4*)&x[16] = rp[4];
            float mx = x[0];
#pragma unroll
            for (int c = 1; c < NCL; ++c) mx = fmaxf(mx, x[c]);
            float e[NCL];
            float ssum = 0.f;
#pragma unroll
            for (int c = 0; c < NCL; ++c) { e[c] = expf(x[c] - mx); ssum += e[c]; }
#pragma unroll
            for (int c = 0; c < NCL; ++c) prob_lds[c][q] = e[c] / ssum;
        }
    }

    // ---- per-lane register state ----
    const float2* pc = (const float2*)pred_coords + (size_t)b * QN;
    float2 pcr[16];
    float  vv[16];
#pragma unroll
    for (int s = 0; s < 16; ++s) {
        int c = s * 64 + lane;
        pcr[s] = pc[c];
        vv[s] = 0.f;
        row4col_s[c] = -1;
    }
    // rows distributed: lane owns rows lane and lane+64
    const int*    labs = tgt_labels + (size_t)b * TN;
    const float2* tj   = (const float2*)tgt_joints + (size_t)b * TN;
    int    labA = labs[lane],        labB = labs[lane + 64];
    float2 tA   = tj[lane],          tB   = tj[lane + 64];
    float  u0 = 0.f, u1 = 0.f;

    col4row_s[lane] = -1;
    col4row_s[lane + 64] = -1;
    __syncthreads();

    for (int cur = 0; cur < TN; ++cur) {
        float sp[16];
        int   pth[16];
        unsigned scMask = 0;
#pragma unroll
        for (int s = 0; s < 16; ++s) { sp[s] = INFV; pth[s] = 0; }

        float minVal = 0.f;
        int i = cur;
        int sink = -1;

        // ---- shortest augmenting path; all-register inner loop ----
        for (int guard = 0; sink < 0 && guard < TN + 2; ++guard) {
            const bool hi = (i & 64) != 0;          // uniform
            const int  src = i & 63;
            float u_i = __shfl(hi ? u1   : u0,   src);
            int   lab = __shfl(hi ? labB : labA, src);
            float tx  = __shfl(hi ? tA.x : tA.x * 0.f + (hi ? tB.x : tA.x), src); // placeholder avoided below
            // (clean broadcasts:)
            tx        = __shfl(hi ? tB.x : tA.x, src);
            float ty  = __shfl(hi ? tB.y : tA.y, src);
            const float* prow = &prob_lds[0][0] + (size_t)lab * QN;

#pragma unroll
            for (int s = 0; s < 16; ++s) {
                int c = s * 64 + lane;
                float pr = prow[c];
                float cb = fabsf(pcr[s].x - tx) + fabsf(pcr[s].y - ty);
                float cost = cb - pr;                       // cb + (-prob)
                float r = ((minVal + cost) - u_i) - vv[s];  // reference op order
                bool upd = (((scMask >> s) & 1u) == 0u) && (r < sp[s]);
                sp[s]  = upd ? r : sp[s];
                pth[s] = upd ? i : pth[s];
            }

            // masked argmin, first-index tie-break (matches jnp.argmin)
            float bv = INFV;
            int   bi = 0x7fffffff;
#pragma unroll
            for (int s = 0; s < 16; ++s) {
                float val = ((scMask >> s) & 1u) ? INFV : sp[s];
                int c = s * 64 + lane;
                if (val < bv) { bv = val; bi = c; }   // ascending c per lane
            }
#pragma unroll
            for (int off = 32; off > 0; off >>= 1) {
                float ov = __shfl_xor(bv, off);
                int   oi = __shfl_xor(bi, off);
                if (ov < bv || (ov == bv && oi < bi)) { bv = ov; bi = oi; }
            }
            minVal = bv;
            const int j = bi;                          // uniform

            if (lane == (j & 63)) scMask |= 1u << (j >> 6);
            int rj = row4col_s[j];                     // uniform LDS read
            sink = (rj < 0) ? j : -1;
            i = rj;
        }

        // ---- dump lane-owned state for cross-lane phases ----
#pragma unroll
        for (int s = 0; s < 16; ++s) {
            int c = s * 64 + lane;
            spc_d[c]  = sp[s];
            sc_d[c]   = (scMask >> s) & 1u;
            path_s[c] = pth[s];
        }
        __syncthreads();

        // ---- dual updates (exactly as reference) ----
        if (lane == (cur & 63)) {
            if (cur & 64) u1 += minVal; else u0 += minVal;
        }
        {
            int c4 = col4row_s[lane];
            if (lane != cur && c4 >= 0 && sc_d[c4]) u0 += minVal - spc_d[c4];
        }
        {
            int rr = lane + 64;
            int c4 = col4row_s[rr];
            if (rr != cur && c4 >= 0 && sc_d[c4]) u1 += minVal - spc_d[c4];
        }
#pragma unroll
        for (int s = 0; s < 16; ++s) {
            if ((scMask >> s) & 1u) vv[s] -= (minVal - sp[s]);
        }
        __syncthreads();

        // ---- augment along alternating path (serial, lane 0) ----
        if (lane == 0) {
            int j = sink;
            for (int it = 0; it <= TN; ++it) {
                int ii = path_s[j];
                row4col_s[j] = ii;
                int nj = col4row_s[ii];
                col4row_s[ii] = j;
                j = nj;
                if (ii == cur) break;
            }
        }
        __syncthreads();
    }

    // ---- outputs: rank = #smaller (col4row values are distinct) ----
    for (int t = lane; t < TN; t += 64) {
        int q = col4row_s[t];
        int rank = 0;
        for (int s = 0; s < TN; ++s) rank += (col4row_s[s] < q) ? 1 : 0;
        out[(size_t)b * TN + rank] = q;            // pred_idx
        out[(size_t)(BSZ + b) * TN + rank] = t;    // tgt_idx
    }
}

extern "C" void kernel_launch(void* const* d_in, const int* in_sizes, int n_in,
                              void* d_out, int out_size, void* d_ws, size_t ws_size,
                              hipStream_t stream) {
    const float* pred_logits = (const float*)d_in[0]; // (B,Q,NC)
    const float* pred_coords = (const float*)d_in[1]; // (B,Q,2)
    const int*   tgt_labels  = (const int*)d_in[2];   // (B,T)
    const float* tgt_joints  = (const float*)d_in[3]; // (B,T,2)

    lsa_fused_kernel<<<BSZ, 64, 0, stream>>>(pred_logits, pred_coords,
                                             tgt_labels, tgt_joints,
                                             (int*)d_out);
}

// Round 3
// 249.638 us; speedup vs baseline: 3.1359x; 1.4086x over previous
//
#include <hip/hip_runtime.h>

#define BSZ 64
#define QN  1024
#define TN  128
#define NCL 20
#define INFV 1e30f

typedef float f32x2 __attribute__((ext_vector_type(2)));
typedef float f32x4 __attribute__((ext_vector_type(4)));

template<int CTRL>
__device__ __forceinline__ float dpp_min(float x) {
    int r = __builtin_amdgcn_mov_dpp(__float_as_int(x), CTRL, 0xF, 0xF, false);
    return fminf(x, __int_as_float(r));
}
// cross-32 exchange, direction-robust (min over self + both swap outputs)
__device__ __forceinline__ float swap32_min(float x) {
    float a = x, b = x;
    asm volatile("v_permlane32_swap_b32 %0, %1" : "+v"(a), "+v"(b));
    return fminf(x, fminf(a, b));
}
__device__ __forceinline__ float swap16_min(float x) {
    float a = x, b = x;
    asm volatile("v_permlane16_swap_b32 %0, %1" : "+v"(a), "+v"(b));
    return fminf(x, fminf(a, b));
}
__device__ __forceinline__ int rdl(int v, int l) {
    return __builtin_amdgcn_readlane(v, l);
}
__device__ __forceinline__ float rdlf(float v, int l) {
    return __int_as_float(__builtin_amdgcn_readlane(__float_as_int(v), l));
}
// permuted LDS index: c = i16*16 + jj*4 + rr  ->  jj*256 + i16*4 + rr
__device__ __forceinline__ int pidxf(int c) {
    return ((c >> 2) & 3) * 256 + ((c >> 4) << 2) + (c & 3);
}

__global__ __launch_bounds__(64) void lsa_fused_kernel(
    const float* __restrict__ pred_logits, // (B,Q,NC)
    const float* __restrict__ pred_coords, // (B,Q,2)
    const int*   __restrict__ tgt_labels,  // (B,T)
    const float* __restrict__ tgt_joints,  // (B,T,2)
    int*         __restrict__ out)         // pred_idx (B,T) ++ tgt_idx (B,T)
{
    const int b = blockIdx.x;
    const int lane = threadIdx.x;

    __shared__ __align__(16) float probP[NCL * QN]; // 80 KB, permuted layout
    __shared__ __align__(16) float cmS[QN];         // 4 KB (frozen spc, INFV = not-in-SC)
    __shared__ int c4rS[TN];

    // ---- stage softmax(logits) into LDS (permuted store) ----
    {
        const float* lg = pred_logits + (size_t)b * QN * NCL;
#pragma unroll
        for (int k = 0; k < 16; ++k) {
            int q = k * 64 + lane;
            const f32x4* rp = (const f32x4*)(lg + (size_t)q * NCL); // 80B rows, 16B aligned
            float x[NCL];
            *(f32x4*)&x[0]  = rp[0];
            *(f32x4*)&x[4]  = rp[1];
            *(f32x4*)&x[8]  = rp[2];
            *(f32x4*)&x[12] = rp[3];
            *(f32x4*)&x[16] = rp[4];
            float mx = x[0];
#pragma unroll
            for (int c = 1; c < NCL; ++c) mx = fmaxf(mx, x[c]);
            float e[NCL];
            float ssum = 0.f;
#pragma unroll
            for (int c = 0; c < NCL; ++c) { e[c] = expf(x[c] - mx); ssum += e[c]; }
            int pq = pidxf(q);
#pragma unroll
            for (int c = 0; c < NCL; ++c) probP[c * QN + pq] = e[c] / ssum;
        }
    }

    // ---- per-lane register state (column c = lane*16 + s) ----
    const float2* pc = (const float2*)pred_coords + (size_t)b * QN;
    f32x2 pxp[8], pyp[8], vvp[8];
    int   rc[16];                       // row4col for owned columns
#pragma unroll
    for (int s = 0; s < 16; ++s) {
        float2 P = pc[lane * 16 + s];
        pxp[s >> 1][s & 1] = P.x;
        pyp[s >> 1][s & 1] = P.y;
        vvp[s >> 1][s & 1] = 0.f;
        rc[s] = -1;
    }
    // rows distributed: lane owns rows lane (A) and lane+64 (B)
    const int*    labs = tgt_labels + (size_t)b * TN;
    const float2* tj   = (const float2*)tgt_joints + (size_t)b * TN;
    int    labA = labs[lane],  labB = labs[lane + 64];
    float2 tA   = tj[lane],    tB   = tj[lane + 64];
    float  u0 = 0.f, u1 = 0.f;
    int    c4rA = -1, c4rB = -1;        // col4row for owned rows
    __syncthreads();

    for (int cur = 0; cur < TN; ++cur) {
        float sp[16];
        int   pth[16];
        unsigned scMask = 0;
#pragma unroll
        for (int s = 0; s < 16; ++s) { sp[s] = INFV; pth[s] = 0; }

        float minVal = 0.f;
        int   i_s = cur;
        int   sinkJ = -1;
        int   iters = 0;

        while (true) {
            // ---- broadcast row i data (uniform i_s -> readlane) ----
            const int  l6 = i_s & 63;
            const bool hi = i_s >= 64;
            int   labI = rdl(hi ? labB : labA, l6);
            float tx   = rdlf(hi ? tB.x : tA.x, l6);
            float ty   = rdlf(hi ? tB.y : tA.y, l6);
            float u_i  = rdlf(hi ? u1 : u0, l6);

            // ---- relax 16 owned columns (packed f32x2 arithmetic) ----
            f32x4 pr4[4];
#pragma unroll
            for (int jj = 0; jj < 4; ++jj)
                pr4[jj] = *(const f32x4*)&probP[labI * QN + jj * 256 + lane * 4];

            f32x2 tx2 = {tx, tx}, ty2 = {ty, ty};
            f32x2 mv2 = {minVal, minVal}, ui2 = {u_i, u_i};
            float mval[16];
#pragma unroll
            for (int p = 0; p < 8; ++p) {
                f32x2 pr;
                pr[0] = pr4[p >> 1][(p & 1) * 2 + 0];
                pr[1] = pr4[p >> 1][(p & 1) * 2 + 1];
                f32x2 dx = pxp[p] - tx2;
                f32x2 dy = pyp[p] - ty2;
                f32x2 cb = __builtin_elementwise_abs(dx) + __builtin_elementwise_abs(dy);
                f32x2 cost = cb - pr;                      // bbox + (-prob)
                f32x2 r2 = ((mv2 + cost) - ui2) - vvp[p];  // reference op order
#pragma unroll
                for (int e = 0; e < 2; ++e) {
                    const int s = p * 2 + e;
                    bool unm = ((scMask >> s) & 1u) == 0u;
                    float r = r2[e];
                    bool upd = unm && (r < sp[s]);
                    sp[s]  = upd ? r   : sp[s];
                    pth[s] = upd ? i_s : pth[s];
                    mval[s] = unm ? sp[s] : INFV;          // masked val for argmin
                }
            }

            // ---- lane-local argmin over 16 slots (first-index tie-break) ----
            float v8[8]; int i8[8];
#pragma unroll
            for (int k = 0; k < 8; ++k) {
                bool t = mval[2 * k + 1] < mval[2 * k];
                v8[k] = t ? mval[2 * k + 1] : mval[2 * k];
                i8[k] = t ? 2 * k + 1 : 2 * k;
            }
            float v4[4]; int i4[4];
#pragma unroll
            for (int k = 0; k < 4; ++k) {
                bool t = v8[2 * k + 1] < v8[2 * k];
                v4[k] = t ? v8[2 * k + 1] : v8[2 * k];
                i4[k] = t ? i8[2 * k + 1] : i8[2 * k];
            }
            float v2[2]; int i2[2];
#pragma unroll
            for (int k = 0; k < 2; ++k) {
                bool t = v4[2 * k + 1] < v4[2 * k];
                v2[k] = t ? v4[2 * k + 1] : v4[2 * k];
                i2[k] = t ? i4[2 * k + 1] : i4[2 * k];
            }
            bool tt = v2[1] < v2[0];
            float lmin = tt ? v2[1] : v2[0];
            int   bi = lane * 16 + (tt ? i2[1] : i2[0]);

            // ---- VALU-only cross-lane min (no ds-pipe on the chain) ----
            float g = swap32_min(lmin);
            g = swap16_min(g);
            g = dpp_min<0x128>(g);   // row_ror:8
            g = dpp_min<0x124>(g);   // row_ror:4
            g = dpp_min<0x122>(g);   // row_ror:2
            g = dpp_min<0x121>(g);   // row_ror:1
            float gmin = __int_as_float(
                __builtin_amdgcn_readfirstlane(__float_as_int(g)));

            // first matching lane = lowest column prefix (lane-major ownership)
            unsigned long long mk = __ballot(lmin == gmin);
            int L = __ffsll(mk) - 1;
            int j_s = rdl(bi, L);
            minVal = gmin;

            // ---- SC add + sink test via register row4col ----
            const int owner = j_s >> 4, slot = j_s & 15;
            if (lane == owner) scMask |= (1u << slot);
            int selrc = rc[0];
#pragma unroll
            for (int s = 1; s < 16; ++s) selrc = (s == slot) ? rc[s] : selrc;
            int rj = rdl(selrc, owner);
            sinkJ = j_s;
            if (rj < 0 || ++iters > TN + 2) break;
            i_s = rj;
        }

        // ---- dump frozen spc (sentinel INFV for non-SC), permuted b128 ----
        float cm[16];
#pragma unroll
        for (int s = 0; s < 16; ++s)
            cm[s] = ((scMask >> s) & 1u) ? sp[s] : INFV;
#pragma unroll
        for (int jj = 0; jj < 4; ++jj) {
            f32x4 w;
            w[0] = cm[jj * 4 + 0]; w[1] = cm[jj * 4 + 1];
            w[2] = cm[jj * 4 + 2]; w[3] = cm[jj * 4 + 3];
            *(f32x4*)&cmS[jj * 256 + lane * 4] = w;
        }
        __syncthreads();

        // ---- dual updates (reference semantics) ----
        if (lane == (cur & 63)) {
            if (cur >= 64) u1 += minVal; else u0 += minVal;
        }
        {
            int c4 = c4rA;
            if (lane != cur && c4 >= 0) {
                float w = cmS[pidxf(c4)];
                if (w < 5e29f) u0 += minVal - w;
            }
        }
        {
            int rr = lane + 64, c4 = c4rB;
            if (rr != cur && c4 >= 0) {
                float w = cmS[pidxf(c4)];
                if (w < 5e29f) u1 += minVal - w;
            }
        }
#pragma unroll
        for (int s = 0; s < 16; ++s) {
            if ((scMask >> s) & 1u)
                vvp[s >> 1][s & 1] -= (minVal - sp[s]);
        }
        __syncthreads();

        // ---- augment along alternating path (register walk, uniform) ----
        {
            int j = sinkJ;
            for (int it = 0; it <= TN; ++it) {
                const int slot = j & 15, owner = j >> 4;
                int selp = pth[0];
#pragma unroll
                for (int s = 1; s < 16; ++s) selp = (s == slot) ? pth[s] : selp;
                int i = rdl(selp, owner);
#pragma unroll
                for (int s = 0; s < 16; ++s)
                    rc[s] = (lane == owner && s == slot) ? i : rc[s];
                const int cown = i & 63;
                const bool hi2 = i >= 64;
                int selc = hi2 ? c4rB : c4rA;
                int nj = rdl(selc, cown);
                if (lane == cown) { if (hi2) c4rB = j; else c4rA = j; }
                j = nj;
                if (i == cur) break;
            }
        }
    }

    // ---- outputs: rank = #smaller (col4row values are distinct) ----
    c4rS[lane] = c4rA;
    c4rS[lane + 64] = c4rB;
    __syncthreads();
#pragma unroll
    for (int h = 0; h < 2; ++h) {
        int t = lane + h * 64;
        int q = h ? c4rB : c4rA;
        int rank = 0;
        for (int s = 0; s < TN; ++s) rank += (c4rS[s] < q) ? 1 : 0;
        out[(size_t)b * TN + rank] = q;            // pred_idx
        out[(size_t)(BSZ + b) * TN + rank] = t;    // tgt_idx
    }
}

extern "C" void kernel_launch(void* const* d_in, const int* in_sizes, int n_in,
                              void* d_out, int out_size, void* d_ws, size_t ws_size,
                              hipStream_t stream) {
    const float* pred_logits = (const float*)d_in[0]; // (B,Q,NC)
    const float* pred_coords = (const float*)d_in[1]; // (B,Q,2)
    const int*   tgt_labels  = (const int*)d_in[2];   // (B,T)
    const float* tgt_joints  = (const float*)d_in[3]; // (B,T,2)

    lsa_fused_kernel<<<BSZ, 64, 0, stream>>>(pred_logits, pred_coords,
                                             tgt_labels, tgt_joints,
                                             (int*)d_out);
}